// Round 7
// baseline (2857.570 us; speedup 1.0000x reference)
//
#include <hip/hip_runtime.h>
#include <hip/hip_fp16.h>

typedef _Float16 half_t;
typedef __attribute__((ext_vector_type(8))) _Float16 f16x8;
typedef __attribute__((ext_vector_type(4))) float f32x4;

#define DIM   3072
#define NH    24
#define DH    128
#define MLP_D 12288
#define LSEQ  4096
#define BATCH 2
#define NROWS 8192           // B*L
#define N1    21504          // 3*DIM + MLP
#define QKV_N 9216           // 3*DIM
#define CAT_N 15360          // DIM + MLP

__device__ __forceinline__ void gload16(const void* g, void* l) {
  __builtin_amdgcn_global_load_lds((const __attribute__((address_space(1))) void*)g,
                                   (__attribute__((address_space(3))) void*)l, 16, 0, 0);
}

__device__ __forceinline__ float gelu_tanh(float x) {
  float u = 0.7978845608028654f * (x + 0.044715f * x * x * x);
  float t = 1.f - 2.f / (__expf(2.f * u) + 1.f);   // tanh(u)
  return 0.5f * x * (1.f + t);
}

struct EpiParams {
  const float* bias;
  float* outF; int ldoF;
  half_t* o1; int ldo1;   // qkv dest (EPI0)
  half_t* o2; int ldo2;   // concat dest (EPI0 gelu part, EPI2)
  const float* resid;
  const float* gate;      // emb+6144, stride 9216 per batch
  float scale;
};

// ============================================================================
// 256x256 tile, BK=32, 8 waves (2M x 4N). 4-deep LDS ring (4 x 32KB buffers):
// staging NEVER targets a buffer being read -> ONE barrier per K-tile, placed
// BETWEEN the two MFMA half-clusters so post-barrier fragment reads (next
// tile's mh0+B frags) overlap the mh1 MFMA cluster. Counted vmcnt(8/4/0),
// setprio around MFMA clusters, compiler-managed lgkmcnt.
// LDS buffer r (= tile&3) at r*32KB: A [256r][32c] @0 (16KB), B @+16KB.
// 16B-chunk XOR swizzle phys = logical ^ ((row>>1)&3); staging applies the
// inverse perm on the GLOBAL source, LDS dest stays linear (rule #21).
// ============================================================================
template<int EPI>
__global__ __launch_bounds__(512, 2) void gemm256(
    const half_t* __restrict__ A, int lda,
    const half_t* __restrict__ B, int ldb,
    int nbx, int nby, int nsplit, int K, EpiParams ep)
{
  __shared__ __align__(16) char lds[131072];
  const int t = threadIdx.x, lane = t & 63, wid = t >> 6;

  // ---- block swizzle: XCD-contiguous chunks + 8-M-block supertile ----
  const int nwg = nbx * nby;
  const int wg = blockIdx.x;
  const int id = (wg & 7) * (nwg >> 3) + (wg >> 3);   // bijective (nwg%8==0)
  const int panel = 8 * nbx;
  const int bm = (id / panel) * 8 + (id % 8);
  const int bn = (id % panel) / 8;
  const int brow = bm * 256, bcol = bn * 256;
  const int wr = wid >> 2, wc = wid & 3;              // 2 x 4 waves

  f32x4 acc[8][4];
#pragma unroll
  for (int m = 0; m < 8; ++m)
#pragma unroll
    for (int n = 0; n < 4; ++n) acc[m][n] = (f32x4){0.f, 0.f, 0.f, 0.f};

  // ---- staging: lane l -> row l>>2 (+16), chunk l&3; global source chunk
  // inverse-permuted: src = (l&3) ^ ((row>>1)&3) = (l&3) ^ ((l>>3)&3)
  const int scol = (((lane & 3) ^ ((lane >> 3) & 3)) * 8);   // elements
  const half_t* pA = A + (size_t)(brow + wid * 32 + (lane >> 2)) * lda + scol;
  const half_t* pB = B + (size_t)(bcol + wid * 32 + (lane >> 2)) * ldb + scol;
  const int wrow = wid * 2048;          // wave's 32 rows (64B each)
  const int NT = K >> 5;

  // ---- fragment read offsets: row = (lane&15), chunk_log = lane>>4,
  // phys = chunk_log ^ ((row>>1)&3) ----
  const int pc = (((lane >> 4) ^ ((lane >> 1) & 3)) << 4);   // bytes
  const int arow = (wr * 128 + (lane & 15)) * 64 + pc;       // + mi*1024
  const int brow_o = 16384 + (wc * 64 + (lane & 15)) * 64 + pc; // + nj*1024

  f16x8 af[4], af2[4], bfA[4], bfB[4];

#define STAGE(tk) {                                                         \
    char* sb = lds + (((tk) & 3) << 15);                                    \
    const half_t* ga = pA + (size_t)(tk) * 32;                              \
    const half_t* gb = pB + (size_t)(tk) * 32;                              \
    gload16(ga, sb + wrow);                                                 \
    gload16(ga + (size_t)16 * lda, sb + wrow + 1024);                       \
    gload16(gb, sb + 16384 + wrow);                                         \
    gload16(gb + (size_t)16 * ldb, sb + 16384 + wrow + 1024); }

#define MFMAC(base, AF, BF)                                                 \
    __builtin_amdgcn_s_setprio(1);                                          \
    _Pragma("unroll")                                                       \
    for (int mi = 0; mi < 4; ++mi)                                          \
      _Pragma("unroll")                                                     \
      for (int nj = 0; nj < 4; ++nj)                                        \
        acc[(base) + mi][nj] = __builtin_amdgcn_mfma_f32_16x16x32_f16(      \
            AF[mi], BF[nj], acc[(base) + mi][nj], 0, 0, 0);                 \
    __builtin_amdgcn_s_setprio(0);

  // BODY: one K-tile. BFC = current B frags, BFN = next tile's B frags.
#define BODY(tt, BFC, BFN) {                                                \
    char* cb = lds + (((tt) & 3) << 15);                                    \
    af2[0] = *(const f16x8*)(cb + arow + 4096);                             \
    af2[1] = *(const f16x8*)(cb + arow + 5120);                             \
    af2[2] = *(const f16x8*)(cb + arow + 6144);                             \
    af2[3] = *(const f16x8*)(cb + arow + 7168);                             \
    MFMAC(0, af, BFC)                                                       \
    if ((tt) + 3 < NT) STAGE((tt) + 3);                                     \
    __builtin_amdgcn_sched_barrier(0);                                      \
    if ((tt) + 3 < NT)      asm volatile("s_waitcnt vmcnt(8)" ::: "memory");\
    else if ((tt) + 2 < NT) asm volatile("s_waitcnt vmcnt(4)" ::: "memory");\
    else                    asm volatile("s_waitcnt vmcnt(0)" ::: "memory");\
    __builtin_amdgcn_s_barrier();                                           \
    __builtin_amdgcn_sched_barrier(0);                                      \
    if ((tt) + 1 < NT) {                                                    \
      char* fb = lds + ((((tt) + 1) & 3) << 15);                            \
      af[0] = *(const f16x8*)(fb + arow);                                   \
      af[1] = *(const f16x8*)(fb + arow + 1024);                            \
      af[2] = *(const f16x8*)(fb + arow + 2048);                            \
      af[3] = *(const f16x8*)(fb + arow + 3072);                            \
      BFN[0] = *(const f16x8*)(fb + brow_o);                                \
      BFN[1] = *(const f16x8*)(fb + brow_o + 1024);                         \
      BFN[2] = *(const f16x8*)(fb + brow_o + 2048);                         \
      BFN[3] = *(const f16x8*)(fb + brow_o + 3072);                         \
    }                                                                       \
    MFMAC(4, af2, BFC)                                                      \
  }

  // ---- prologue: stage tiles 0..2; pre-read tile 0 frags ----
  STAGE(0); STAGE(1); STAGE(2);
  asm volatile("s_waitcnt vmcnt(8)" ::: "memory");   // tile 0 landed
  __builtin_amdgcn_s_barrier();
  __builtin_amdgcn_sched_barrier(0);
  af[0] = *(const f16x8*)(lds + arow);
  af[1] = *(const f16x8*)(lds + arow + 1024);
  af[2] = *(const f16x8*)(lds + arow + 2048);
  af[3] = *(const f16x8*)(lds + arow + 3072);
  bfA[0] = *(const f16x8*)(lds + brow_o);
  bfA[1] = *(const f16x8*)(lds + brow_o + 1024);
  bfA[2] = *(const f16x8*)(lds + brow_o + 2048);
  bfA[3] = *(const f16x8*)(lds + brow_o + 3072);

  for (int tt = 0; tt < NT; tt += 2) {   // NT always even here
    BODY(tt, bfA, bfB)
    BODY(tt + 1, bfB, bfA)
  }
#undef STAGE
#undef MFMAC
#undef BODY

  // ---- epilogue ----
  const int laneR = lane & 15;
  const int colb = bcol + wc * 64;
  const int rowb = brow + wr * 128 + (lane >> 4) * 4;
#pragma unroll
  for (int mi = 0; mi < 8; ++mi) {
#pragma unroll
    for (int nj = 0; nj < 4; ++nj) {
      int col = colb + nj * 16 + laneR;
#pragma unroll
      for (int j = 0; j < 4; ++j) {
        int row = rowb + mi * 16 + j;
        float v = acc[mi][nj][j];
        if (EPI == 0) {
          v += ep.bias[col];
          if (col < nsplit) {
            ep.o1[(size_t)row * ep.ldo1 + col] = (half_t)v;
          } else {
            ep.o2[(size_t)row * ep.ldo2 + DIM + (col - nsplit)] = (half_t)gelu_tanh(v);
          }
        } else if (EPI == 1) {
          ep.outF[(size_t)row * ep.ldoF + col] = v * ep.scale;
        } else if (EPI == 2) {
          ep.o2[(size_t)row * ep.ldo2 + col] = (half_t)v;
        } else {
          v += ep.bias[col];
          int b = row >> 12;
          float g = ep.gate[(size_t)b * QKV_N + col];
          float r = ep.resid[(size_t)row * DIM + col];
          ep.outF[(size_t)row * ep.ldoF + col] = r + g * v;
        }
      }
    }
  }
}

// emb = silu(temb) @ w_lin + b_lin   (2 x 9216)
__global__ __launch_bounds__(256) void k_emb(
    const float* __restrict__ temb, const float* __restrict__ w_lin,
    const float* __restrict__ b_lin, float* __restrict__ emb)
{
  __shared__ float s[DIM];
  int b = blockIdx.y;
  int col = blockIdx.x * 256 + threadIdx.x;
  const float* tr = temb + (size_t)b * DIM;
  for (int k = threadIdx.x; k < DIM; k += 256) {
    float x = tr[k];
    s[k] = x / (1.f + __expf(-x));
  }
  __syncthreads();
  float acc = b_lin[col];
  for (int k = 0; k < DIM; k += 4) {
    acc += s[k] * w_lin[(size_t)k * QKV_N + col]
         + s[k + 1] * w_lin[(size_t)(k + 1) * QKV_N + col]
         + s[k + 2] * w_lin[(size_t)(k + 2) * QKV_N + col]
         + s[k + 3] * w_lin[(size_t)(k + 3) * QKV_N + col];
  }
  emb[(size_t)b * QKV_N + col] = acc;
}

// LayerNorm + (1+scale)*xhat + shift -> fp16
__global__ __launch_bounds__(256) void k_lnmod(
    const float* __restrict__ hs, const float* __restrict__ emb,
    half_t* __restrict__ xmod)
{
  int row = blockIdx.x;
  int b = row >> 12;
  const float* x = hs + (size_t)row * DIM;
  int t = threadIdx.x;
  float s = 0.f, s2 = 0.f;
  float4 v[3];
#pragma unroll
  for (int i = 0; i < 3; ++i) {
    v[i] = ((const float4*)x)[t + 256 * i];
    s  += v[i].x + v[i].y + v[i].z + v[i].w;
    s2 += v[i].x * v[i].x + v[i].y * v[i].y + v[i].z * v[i].z + v[i].w * v[i].w;
  }
  for (int o = 32; o; o >>= 1) { s += __shfl_xor(s, o); s2 += __shfl_xor(s2, o); }
  __shared__ float rs[4], rs2[4];
  int lane = t & 63, w = t >> 6;
  if (lane == 0) { rs[w] = s; rs2[w] = s2; }
  __syncthreads();
  s = rs[0] + rs[1] + rs[2] + rs[3];
  s2 = rs2[0] + rs2[1] + rs2[2] + rs2[3];
  float mu = s * (1.f / DIM);
  float var = s2 * (1.f / DIM) - mu * mu;
  float rstd = rsqrtf(var + 1e-6f);
  const float* shift = emb + (size_t)b * QKV_N;
  const float* scale = shift + DIM;
#pragma unroll
  for (int i = 0; i < 3; ++i) {
    int g = t + 256 * i;
    float4 sc = ((const float4*)scale)[g];
    float4 sh = ((const float4*)shift)[g];
    half_t ob[4];
    float vv[4] = {v[i].x, v[i].y, v[i].z, v[i].w};
    float scv[4] = {sc.x, sc.y, sc.z, sc.w};
    float shv[4] = {sh.x, sh.y, sh.z, sh.w};
#pragma unroll
    for (int j = 0; j < 4; ++j) {
      float xn = (vv[j] - mu) * rstd;
      ob[j] = (half_t)(xn * (1.f + scv[j]) + shv[j]);
    }
    *(uint2*)&xmod[(size_t)row * DIM + g * 4] = *(uint2*)ob;
  }
}

// f32 (RxC) -> fp16 transposed (CxR)
__global__ __launch_bounds__(256) void k_transpose_cvt(
    const float* __restrict__ in, half_t* __restrict__ out, int R, int C)
{
  __shared__ float s[64][65];
  int c0 = blockIdx.x * 64, r0 = blockIdx.y * 64;
  int tx = threadIdx.x & 63, ty = threadIdx.x >> 6;
#pragma unroll
  for (int j = 0; j < 16; ++j) {
    int r = ty + j * 4;
    s[r][tx] = in[(size_t)(r0 + r) * C + c0 + tx];
  }
  __syncthreads();
#pragma unroll
  for (int j = 0; j < 16; ++j) {
    int c = ty + j * 4;
    out[(size_t)(c0 + c) * R + r0 + tx] = (half_t)s[tx][c];
  }
}

// RMS + RoPE on q,k in-place in qkv buffer. One wave per (row, head, q/k).
__global__ __launch_bounds__(256) void k_qk_rmsrope(
    half_t* __restrict__ qkv, const float* __restrict__ rope,
    const float* __restrict__ q_scale, const float* __restrict__ k_scale)
{
  int w = blockIdx.x * 4 + (threadIdx.x >> 6);
  int lane = threadIdx.x & 63;
  int qk = w & 1;
  int hr = w >> 1;               // bl*24 + h
  int h = hr % 24;
  int bl = hr / 24;              // b*4096 + l
  size_t base = (size_t)bl * QKV_N + qk * DIM + h * DH;
  float x0 = (float)qkv[base + lane * 2];
  float x1 = (float)qkv[base + lane * 2 + 1];
  float ss = x0 * x0 + x1 * x1;
  for (int o = 32; o; o >>= 1) ss += __shfl_xor(ss, o);
  float r = rsqrtf(ss * (1.f / DH) + 1e-6f);
  const float* sc = qk ? k_scale : q_scale;
  float xs0 = x0 * r * sc[lane * 2];
  float xs1 = x1 * r * sc[lane * 2 + 1];
  int l = bl & (LSEQ - 1);
  float4 fr = ((const float4*)rope)[(size_t)l * 64 + lane];
  qkv[base + lane * 2]     = (half_t)(fr.x * xs0 + fr.y * xs1);
  qkv[base + lane * 2 + 1] = (half_t)(fr.z * xs0 + fr.w * xs1);
}

// v part of qkv -> vT (per batch: DIM x LSEQ), tiled transpose
__global__ __launch_bounds__(256) void k_vT(
    const half_t* __restrict__ qkv, half_t* __restrict__ vT)
{
  __shared__ half_t s[64][65];
  int b = blockIdx.z;
  int l0 = blockIdx.x * 64, d0 = blockIdx.y * 64;
  int tx = threadIdx.x & 63, ty = threadIdx.x >> 6;
#pragma unroll
  for (int j = 0; j < 16; ++j) {
    int l = ty + j * 4;
    s[l][tx] = qkv[(size_t)(b * LSEQ + l0 + l) * QKV_N + 2 * DIM + d0 + tx];
  }
  __syncthreads();
#pragma unroll
  for (int j = 0; j < 16; ++j) {
    int d = ty + j * 4;
    vT[((size_t)b * DIM + d0 + d) * LSEQ + l0 + tx] = s[tx][d];
  }
}

// row softmax: S (4096 f32) -> P fp16
__global__ __launch_bounds__(256) void k_softmax(
    const float* __restrict__ S, half_t* __restrict__ P)
{
  int row = blockIdx.x;
  const float* srow = S + (size_t)row * LSEQ;
  int t = threadIdx.x;
  float4 v[4];
  float mx = -1e30f;
#pragma unroll
  for (int i = 0; i < 4; ++i) {
    v[i] = ((const float4*)srow)[t + 256 * i];
    mx = fmaxf(mx, fmaxf(fmaxf(v[i].x, v[i].y), fmaxf(v[i].z, v[i].w)));
  }
  for (int o = 32; o; o >>= 1) mx = fmaxf(mx, __shfl_xor(mx, o));
  __shared__ float rmx[4], rsum[4];
  int lane = t & 63, w = t >> 6;
  if (lane == 0) rmx[w] = mx;
  __syncthreads();
  mx = fmaxf(fmaxf(rmx[0], rmx[1]), fmaxf(rmx[2], rmx[3]));
  float s = 0.f;
#pragma unroll
  for (int i = 0; i < 4; ++i) {
    v[i].x = __expf(v[i].x - mx); v[i].y = __expf(v[i].y - mx);
    v[i].z = __expf(v[i].z - mx); v[i].w = __expf(v[i].w - mx);
    s += v[i].x + v[i].y + v[i].z + v[i].w;
  }
  for (int o = 32; o; o >>= 1) s += __shfl_xor(s, o);
  if (lane == 0) rsum[w] = s;
  __syncthreads();
  s = rsum[0] + rsum[1] + rsum[2] + rsum[3];
  float inv = 1.f / s;
#pragma unroll
  for (int i = 0; i < 4; ++i) {
    half_t ob[4] = {
      (half_t)(v[i].x * inv), (half_t)(v[i].y * inv),
      (half_t)(v[i].z * inv), (half_t)(v[i].w * inv)};
    *(uint2*)&P[(size_t)row * LSEQ + (t + 256 * i) * 4] = *(uint2*)ob;
  }
}

extern "C" void kernel_launch(void* const* d_in, const int* in_sizes, int n_in,
                              void* d_out, int out_size, void* d_ws, size_t ws_size,
                              hipStream_t stream) {
  const float* hs      = (const float*)d_in[0];
  const float* temb    = (const float*)d_in[1];
  const float* rope    = (const float*)d_in[2];
  const float* w_lin   = (const float*)d_in[3];
  const float* b_lin   = (const float*)d_in[4];
  const float* w1      = (const float*)d_in[5];
  const float* b1      = (const float*)d_in[6];
  const float* w2      = (const float*)d_in[7];
  const float* b2      = (const float*)d_in[8];
  const float* q_scale = (const float*)d_in[9];
  const float* k_scale = (const float*)d_in[10];
  float* out = (float*)d_out;

  char* ws = (char*)d_ws;
  size_t off = 0;
  auto alloc = [&](size_t bytes) { char* p = ws + off; off += (bytes + 255) & ~(size_t)255; return p; };
  float*  emb    = (float*) alloc((size_t)BATCH * QKV_N * 4);
  half_t* xmod   = (half_t*)alloc((size_t)NROWS * DIM * 2);
  half_t* w1T    = (half_t*)alloc((size_t)N1 * DIM * 2);
  half_t* w2T    = (half_t*)alloc((size_t)DIM * CAT_N * 2);
  half_t* qkv    = (half_t*)alloc((size_t)NROWS * QKV_N * 2);
  half_t* concat = (half_t*)alloc((size_t)NROWS * CAT_N * 2);
  half_t* vT     = (half_t*)alloc((size_t)BATCH * DIM * LSEQ * 2);
  float*  Sbuf   = (float*) alloc((size_t)LSEQ * LSEQ * 4);
  half_t* Pbuf   = (half_t*)alloc((size_t)LSEQ * LSEQ * 2);
  (void)ws_size; (void)n_in; (void)in_sizes; (void)out_size;

  k_emb<<<dim3(QKV_N / 256, BATCH), 256, 0, stream>>>(temb, w_lin, b_lin, emb);
  k_transpose_cvt<<<dim3(N1 / 64, DIM / 64), 256, 0, stream>>>(w1, w1T, DIM, N1);
  k_transpose_cvt<<<dim3(DIM / 64, CAT_N / 64), 256, 0, stream>>>(w2, w2T, CAT_N, DIM);
  k_lnmod<<<NROWS, 256, 0, stream>>>(hs, emb, xmod);

  // GEMM1: proj = xmod @ w1 + b1 ; qkv part -> qkv buf, mlp part -> gelu -> concat[:,3072:]
  EpiParams ep1 = {b1, nullptr, 0, qkv, QKV_N, concat, CAT_N, nullptr, nullptr, 0.f};
  gemm256<0><<<(N1 / 256) * (NROWS / 256), 512, 0, stream>>>(
      xmod, DIM, w1T, DIM, N1 / 256, NROWS / 256, QKV_N, DIM, ep1);

  k_qk_rmsrope<<<(NROWS * NH * 2) / 4, 256, 0, stream>>>(qkv, rope, q_scale, k_scale);
  k_vT<<<dim3(LSEQ / 64, DIM / 64, BATCH), 256, 0, stream>>>(qkv, vT);

  for (int b = 0; b < BATCH; ++b) {
    const half_t* qb = qkv + (size_t)b * LSEQ * QKV_N;
    EpiParams epS = {nullptr, Sbuf, LSEQ, nullptr, 0, nullptr, 0, nullptr, nullptr, 0.08838834764831845f};
    gemm256<1><<<(LSEQ / 256) * (LSEQ / 256), 512, 0, stream>>>(
        qb, QKV_N, qb + DIM, QKV_N, LSEQ / 256, LSEQ / 256, 0, DIM, epS);
    k_softmax<<<LSEQ, 256, 0, stream>>>(Sbuf, Pbuf);
    EpiParams epPV = {nullptr, nullptr, 0, nullptr, 0,
                      concat + (size_t)b * LSEQ * CAT_N, CAT_N, nullptr, nullptr, 0.f};
    gemm256<2><<<(DIM / 256) * (LSEQ / 256), 512, 0, stream>>>(
        Pbuf, LSEQ, vT + (size_t)b * DIM * LSEQ, LSEQ, DIM / 256, LSEQ / 256, 0, LSEQ, epPV);
  }

  // GEMM2: out = resid + gate * (concat @ w2 + b2)
  EpiParams ep2 = {b2, out, DIM, nullptr, 0, nullptr, 0, hs, emb + 2 * DIM, 0.f};
  gemm256<3><<<(DIM / 256) * (NROWS / 256), 512, 0, stream>>>(
      concat, CAT_N, w2T, CAT_N, DIM / 256, NROWS / 256, 0, CAT_N, ep2);
}